// Round 8
// baseline (4337.323 us; speedup 1.0000x reference)
//
#include <hip/hip_runtime.h>
#include <math.h>

#define BATCH 16
#define SEQ 512
#define DIM 2048
#define HID 1024
#define NPAIRS 128
#define TLEN 384
#define NUN 256
#define BK 32

// ---------------------------------------------------------------------------
// GEMM 1: h = gelu(x @ imp_w1 + b1). fp64 accumulate (ascending k — bit-exact
// vs rounds 4-7), f64 tiles in LDS. 64x64 tile, BK=32.  (selection path!)
// ---------------------------------------------------------------------------
__global__ __launch_bounds__(256)
void cc_gemm_h(const float* __restrict__ A, const float* __restrict__ Bw,
               const float* __restrict__ bias, float* __restrict__ C) {
  const int N = HID, K = DIM;
  __shared__ double As[BK][66];
  __shared__ double Bs[BK][66];
  int tid = threadIdx.x;
  int tx = tid % 16, ty = tid / 16;
  int m0 = blockIdx.y * 64, n0 = blockIdx.x * 64;
  double acc[4][4] = {};
  for (int k0 = 0; k0 < K; k0 += BK) {
#pragma unroll
    for (int u = 0; u < 8; ++u) {
      int l = tid + u * 256;
      int r = l >> 5, k = l & 31;
      As[k][r] = (double)A[(size_t)(m0 + r) * K + k0 + k];
      int kb = l >> 6, n = l & 63;
      Bs[kb][n] = (double)Bw[(size_t)(k0 + kb) * N + n0 + n];
    }
    __syncthreads();
#pragma unroll
    for (int k = 0; k < BK; ++k) {
      double a0 = As[k][ty * 4 + 0], a1 = As[k][ty * 4 + 1];
      double a2 = As[k][ty * 4 + 2], a3 = As[k][ty * 4 + 3];
      double b0 = Bs[k][tx * 4 + 0], b1 = Bs[k][tx * 4 + 1];
      double b2 = Bs[k][tx * 4 + 2], b3 = Bs[k][tx * 4 + 3];
      acc[0][0] = fma(a0, b0, acc[0][0]); acc[0][1] = fma(a0, b1, acc[0][1]);
      acc[0][2] = fma(a0, b2, acc[0][2]); acc[0][3] = fma(a0, b3, acc[0][3]);
      acc[1][0] = fma(a1, b0, acc[1][0]); acc[1][1] = fma(a1, b1, acc[1][1]);
      acc[1][2] = fma(a1, b2, acc[1][2]); acc[1][3] = fma(a1, b3, acc[1][3]);
      acc[2][0] = fma(a2, b0, acc[2][0]); acc[2][1] = fma(a2, b1, acc[2][1]);
      acc[2][2] = fma(a2, b2, acc[2][2]); acc[2][3] = fma(a2, b3, acc[2][3]);
      acc[3][0] = fma(a3, b0, acc[3][0]); acc[3][1] = fma(a3, b1, acc[3][1]);
      acc[3][2] = fma(a3, b2, acc[3][2]); acc[3][3] = fma(a3, b3, acc[3][3]);
    }
    __syncthreads();
  }
#pragma unroll
  for (int i = 0; i < 4; ++i)
#pragma unroll
    for (int j = 0; j < 4; ++j) {
      int m = m0 + ty * 4 + i, n = n0 + tx * 4 + j;
      float pre = (float)(acc[i][j] + (double)bias[n]);     // f32 store point
      double v = (double)pre;
      double g = 0.5 * v * (1.0 + erf(v * 0.70710678118654752440));
      C[(size_t)m * N + n] = (float)g;                      // f32 store point
    }
}

// ---------------------------------------------------------------------------
// imp = sigmoid(h @ imp_w2 + b2); logit rounded to f32, imp stored f32
// ---------------------------------------------------------------------------
__global__ __launch_bounds__(256)
void cc_imp2(const float* __restrict__ h, const float* __restrict__ w2,
             const float* __restrict__ b2, float* __restrict__ imp) {
  int row = blockIdx.x, tid = threadIdx.x;
  __shared__ double red[256];
  double s = 0.0;
  const float* hr = h + (size_t)row * HID;
  for (int k = tid; k < HID; k += 256) s = fma((double)hr[k], (double)w2[k], s);
  red[tid] = s;
  __syncthreads();
  for (int off = 128; off > 0; off >>= 1) {
    if (tid < off) red[tid] += red[tid + off];
    __syncthreads();
  }
  if (tid == 0) {
    float logit = (float)(red[0] + (double)b2[0]);          // f32 store point
    double sg = 1.0 / (1.0 + exp(-(double)logit));
    imp[row] = (float)sg;                                   // f32 store point
  }
}

// ---------------------------------------------------------------------------
// per-batch min-max normalize in f32, then w = max(norm, 0.1f)
// ---------------------------------------------------------------------------
__global__ __launch_bounds__(512)
void cc_minmax(const float* __restrict__ imp, float* __restrict__ w) {
  int b = blockIdx.x, tid = threadIdx.x;
  __shared__ float mn[512], mx[512];
  float v = imp[b * SEQ + tid];
  mn[tid] = v; mx[tid] = v;
  __syncthreads();
  for (int off = 256; off > 0; off >>= 1) {
    if (tid < off) {
      mn[tid] = fminf(mn[tid], mn[tid + off]);
      mx[tid] = fmaxf(mx[tid], mx[tid + off]);
    }
    __syncthreads();
  }
  float lo = mn[0], hi = mx[0];
  float nv = (hi > lo) ? (v - lo) / (hi - lo) : v;
  w[b * SEQ + tid] = fmaxf(nv, 0.1f);
}

// ---------------------------------------------------------------------------
// row L2 norms of x: exact f64 sumsq, sqrt, rounded to f32, clamp 1e-12f
// ---------------------------------------------------------------------------
__global__ __launch_bounds__(256)
void cc_rownorm(const float* __restrict__ x, float* __restrict__ rn) {
  int row = blockIdx.x, tid = threadIdx.x;
  __shared__ double red[256];
  double s = 0.0;
  const float* xr = x + (size_t)row * DIM;
  for (int k = tid; k < DIM; k += 256) {
    double v = xr[k];
    s = fma(v, v, s);
  }
  red[tid] = s;
  __syncthreads();
  for (int off = 128; off > 0; off >>= 1) {
    if (tid < off) red[tid] += red[tid + off];
    __syncthreads();
  }
  if (tid == 0) rn[row] = fmaxf((float)sqrt(red[0]), 1e-12f);
}

// ---------------------------------------------------------------------------
// score[b,s,t]: xn = x/rn (f32 div at staging), f64-exact dot -> f32 sim,
// wprod f32 mul, score = sim/wprod f32 div; diag -1.0f.  BK=32, f64 LDS.
// (identical numerics to rounds 4-7)
// ---------------------------------------------------------------------------
__global__ __launch_bounds__(256)
void cc_gemm_score(const float* __restrict__ X, const float* __restrict__ rn,
                   const float* __restrict__ w, float* __restrict__ score) {
  const int b = blockIdx.z;
  __shared__ double As[BK][66];
  __shared__ double Bs[BK][66];
  int tid = threadIdx.x;
  int tx = tid % 16, ty = tid / 16;
  int s0 = blockIdx.y * 64, t0 = blockIdx.x * 64;
  const float* Xb = X + (size_t)b * SEQ * DIM;
  const float* rnb = rn + b * SEQ;
  double acc[4][4] = {};
  for (int k0 = 0; k0 < DIM; k0 += BK) {
#pragma unroll
    for (int u = 0; u < 8; ++u) {
      int l = tid + u * 256;
      int r = l >> 5, k = l & 31;
      As[k][r] = (double)(Xb[(size_t)(s0 + r) * DIM + k0 + k] / rnb[s0 + r]);
      Bs[k][r] = (double)(Xb[(size_t)(t0 + r) * DIM + k0 + k] / rnb[t0 + r]);
    }
    __syncthreads();
#pragma unroll
    for (int k = 0; k < BK; ++k) {
      double a0 = As[k][ty * 4 + 0], a1 = As[k][ty * 4 + 1];
      double a2 = As[k][ty * 4 + 2], a3 = As[k][ty * 4 + 3];
      double b0 = Bs[k][tx * 4 + 0], b1 = Bs[k][tx * 4 + 1];
      double b2 = Bs[k][tx * 4 + 2], b3 = Bs[k][tx * 4 + 3];
      acc[0][0] = fma(a0, b0, acc[0][0]); acc[0][1] = fma(a0, b1, acc[0][1]);
      acc[0][2] = fma(a0, b2, acc[0][2]); acc[0][3] = fma(a0, b3, acc[0][3]);
      acc[1][0] = fma(a1, b0, acc[1][0]); acc[1][1] = fma(a1, b1, acc[1][1]);
      acc[1][2] = fma(a1, b2, acc[1][2]); acc[1][3] = fma(a1, b3, acc[1][3]);
      acc[2][0] = fma(a2, b0, acc[2][0]); acc[2][1] = fma(a2, b1, acc[2][1]);
      acc[2][2] = fma(a2, b2, acc[2][2]); acc[2][3] = fma(a2, b3, acc[2][3]);
      acc[3][0] = fma(a3, b0, acc[3][0]); acc[3][1] = fma(a3, b1, acc[3][1]);
      acc[3][2] = fma(a3, b2, acc[3][2]); acc[3][3] = fma(a3, b3, acc[3][3]);
    }
    __syncthreads();
  }
#pragma unroll
  for (int i = 0; i < 4; ++i)
#pragma unroll
    for (int j = 0; j < 4; ++j) {
      int s = s0 + ty * 4 + i, t = t0 + tx * 4 + j;
      float v;
      if (s == t) v = -1.0f;
      else {
        float sim = (float)acc[i][j];                       // f32 store point
        float wp = w[b * SEQ + s] * w[b * SEQ + t];         // f32 multiply
        v = sim / wp;                                       // f32 divide
      }
      score[((size_t)b * SEQ + s) * SEQ + t] = v;
    }
}

// ---------------------------------------------------------------------------
// Greedy helpers: packed key = (ordered_f32 << 32) | (511 - idx).
// Bigger key == (larger value, then smaller idx). Finite floats -> hi!=0.
// ---------------------------------------------------------------------------
__device__ __forceinline__ unsigned long long cc_packkey(float v, int idx) {
  unsigned u = __float_as_uint(v);
  unsigned ou = (u & 0x80000000u) ? ~u : (u | 0x80000000u);
  return ((unsigned long long)ou << 32) | (unsigned)((SEQ - 1) - idx);
}
__device__ __forceinline__ void cc_ins4(unsigned long long& l0, unsigned long long& l1,
                                        unsigned long long& l2, unsigned long long& l3,
                                        unsigned long long k) {
  if (k > l3) {
    if (k > l1) {
      if (k > l0) { l3 = l2; l2 = l1; l1 = l0; l0 = k; }
      else        { l3 = l2; l2 = l1; l1 = k; }
    } else {
      if (k > l2) { l3 = l2; l2 = k; }
      else        { l3 = k; }
    }
  }
}

// ---------------------------------------------------------------------------
// Greedy pair selection: 256 threads (4 waves) per batch, top-4 key cache
// per row in LDS.  Head (first alive entry) == exact row max among alive
// cols (uncached keys < all cached keys; deletions only), so the pick
// sequence reproduces flat jnp.argmax tie-breaks exactly.
//  - pick: per-thread head over its 2 rows -> wave shfl max -> LDS combine
//  - rescan only when all 4 cached entries of a row are dead; needy rows
//    distributed across the 4 waves, each rebuilt wave-parallel.
// ---------------------------------------------------------------------------
__global__ __launch_bounds__(256)
void cc_greedy(const float* __restrict__ score, int* __restrict__ pi,
               int* __restrict__ pj, unsigned char* __restrict__ availg) {
  const int b = blockIdx.x;
  const float* S = score + (size_t)b * SEQ * SEQ;
  const int tid = threadIdx.x;
  const int lane = tid & 63;
  const int wave = tid >> 6;

  __shared__ unsigned long long key4[SEQ][5];   // top-4 keys (+1 pad), 20 KB
  __shared__ uint2 availv[SEQ / 8];             // avail bytes
  unsigned char* avail = (unsigned char*)availv;
  __shared__ unsigned long long wkeys[4];
  __shared__ int rlist[SEQ];
  __shared__ int rcnt_s, si_s, sj_s;
  __shared__ int spi[NPAIRS], spj[NPAIRS];

  if (tid < SEQ / 8) availv[tid] = make_uint2(0x01010101u, 0x01010101u);

  // ---- init: each thread builds top-4 for rows 2tid, 2tid+1 ----
  {
    const int r0 = tid * 2;
    unsigned long long a0 = 0, a1 = 0, a2 = 0, a3 = 0;
    unsigned long long b0 = 0, b1 = 0, b2 = 0, b3 = 0;
    const float4* p0 = (const float4*)(S + (size_t)r0 * SEQ);
    const float4* p1 = (const float4*)(S + (size_t)(r0 + 1) * SEQ);
    for (int c4 = 0; c4 < SEQ / 4; ++c4) {
      float4 v = p0[c4], w = p1[c4];
      int cc = c4 * 4;
      cc_ins4(a0, a1, a2, a3, cc_packkey(v.x, cc));
      cc_ins4(a0, a1, a2, a3, cc_packkey(v.y, cc + 1));
      cc_ins4(a0, a1, a2, a3, cc_packkey(v.z, cc + 2));
      cc_ins4(a0, a1, a2, a3, cc_packkey(v.w, cc + 3));
      cc_ins4(b0, b1, b2, b3, cc_packkey(w.x, cc));
      cc_ins4(b0, b1, b2, b3, cc_packkey(w.y, cc + 1));
      cc_ins4(b0, b1, b2, b3, cc_packkey(w.z, cc + 2));
      cc_ins4(b0, b1, b2, b3, cc_packkey(w.w, cc + 3));
    }
    key4[r0][0] = a0; key4[r0][1] = a1; key4[r0][2] = a2; key4[r0][3] = a3;
    key4[r0 + 1][0] = b0; key4[r0 + 1][1] = b1;
    key4[r0 + 1][2] = b2; key4[r0 + 1][3] = b3;
  }
  __syncthreads();

  for (int t = 0; t < NPAIRS; ++t) {
    // ---- step 1: per-thread candidate = best head over its 2 rows ----
    unsigned long long cand = 0;
    int hc0 = -1, hc1 = -1;
#pragma unroll
    for (int rr = 0; rr < 2; ++rr) {
      int r = tid * 2 + rr;
      if (avail[r]) {
        unsigned long long hk = 0; int hc = -1;
#pragma unroll
        for (int q = 0; q < 4; ++q) {
          unsigned long long k = key4[r][q];
          if (!k) break;
          int c = (SEQ - 1) - (int)(k & 0xFFFFFFFFull);
          if (avail[c]) { hk = k; hc = c; break; }
        }
        if (hc >= 0) {
          unsigned long long ck = (hk & 0xFFFFFFFF00000000ull)
                                | (unsigned)((SEQ - 1) - r);
          if (ck > cand) cand = ck;
        }
        if (rr == 0) hc0 = hc; else hc1 = hc;
      }
    }
    // ---- wave + block reduce ----
#pragma unroll
    for (int off = 1; off < 64; off <<= 1) {
      unsigned long long ok = __shfl_xor(cand, off, 64);
      if (ok > cand) cand = ok;
    }
    if (lane == 0) wkeys[wave] = cand;
    __syncthreads();
    if (tid == 0) {
      unsigned long long k = wkeys[0];
      if (wkeys[1] > k) k = wkeys[1];
      if (wkeys[2] > k) k = wkeys[2];
      if (wkeys[3] > k) k = wkeys[3];
      int i = (SEQ - 1) - (int)(k & 0xFFFFFFFFull);
      int j = -1;
#pragma unroll
      for (int q = 0; q < 4; ++q) {
        unsigned long long kk = key4[i][q];
        if (!kk) break;
        int c = (SEQ - 1) - (int)(kk & 0xFFFFFFFFull);
        if (avail[c]) { j = c; break; }
      }
      spi[t] = i; spj[t] = j;
      si_s = i; sj_s = j;
      avail[i] = 0; avail[j] = 0;
      rcnt_s = 0;
    }
    __syncthreads();
    const int si = si_s, sj = sj_s;
    // ---- step 2: rows whose head died and have no alive entry -> rescan ----
    {
      int r = tid * 2;
      if ((hc0 == si || hc0 == sj) && avail[r]) {
        bool any = false;
#pragma unroll
        for (int q = 0; q < 4; ++q) {
          unsigned long long k = key4[r][q];
          if (!k) break;
          int c = (SEQ - 1) - (int)(k & 0xFFFFFFFFull);
          if (avail[c]) { any = true; break; }
        }
        if (!any) { int p = atomicAdd(&rcnt_s, 1); rlist[p] = r; }
      }
      r = tid * 2 + 1;
      if ((hc1 == si || hc1 == sj) && avail[r]) {
        bool any = false;
#pragma unroll
        for (int q = 0; q < 4; ++q) {
          unsigned long long k = key4[r][q];
          if (!k) break;
          int c = (SEQ - 1) - (int)(k & 0xFFFFFFFFull);
          if (avail[c]) { any = true; break; }
        }
        if (!any) { int p = atomicAdd(&rcnt_s, 1); rlist[p] = r; }
      }
    }
    __syncthreads();
    // ---- step 3: waves rebuild needy rows (wave-parallel top-4) ----
    const int rc = rcnt_s;
    for (int idx = wave; idx < rc; idx += 4) {
      int r = rlist[idx];
      const float4* row4 = (const float4*)(S + (size_t)r * SEQ) + lane * 2;
      float4 v0 = row4[0], v1 = row4[1];
      uint2 av = availv[lane];
      unsigned long long l0 = 0, l1 = 0, l2 = 0, l3 = 0;
      int cb = lane * 8;
      if (av.x & 0x000000FFu) cc_ins4(l0, l1, l2, l3, cc_packkey(v0.x, cb + 0));
      if (av.x & 0x0000FF00u) cc_ins4(l0, l1, l2, l3, cc_packkey(v0.y, cb + 1));
      if (av.x & 0x00FF0000u) cc_ins4(l0, l1, l2, l3, cc_packkey(v0.z, cb + 2));
      if (av.x & 0xFF000000u) cc_ins4(l0, l1, l2, l3, cc_packkey(v0.w, cb + 3));
      if (av.y & 0x000000FFu) cc_ins4(l0, l1, l2, l3, cc_packkey(v1.x, cb + 4));
      if (av.y & 0x0000FF00u) cc_ins4(l0, l1, l2, l3, cc_packkey(v1.y, cb + 5));
      if (av.y & 0x00FF0000u) cc_ins4(l0, l1, l2, l3, cc_packkey(v1.z, cb + 6));
      if (av.y & 0xFF000000u) cc_ins4(l0, l1, l2, l3, cc_packkey(v1.w, cb + 7));
#pragma unroll
      for (int e = 0; e < 4; ++e) {
        unsigned long long cur = l0;
        unsigned long long wk = cur;
#pragma unroll
        for (int off = 1; off < 64; off <<= 1) {
          unsigned long long ok = __shfl_xor(wk, off, 64);
          if (ok > wk) wk = ok;
        }
        if (wk != 0ULL && cur == wk) { l0 = l1; l1 = l2; l2 = l3; l3 = 0; }
        if (lane == 0) key4[r][e] = wk;
      }
    }
    __syncthreads();
  }

  for (int t2 = tid; t2 < NPAIRS; t2 += 256) {
    pi[b * NPAIRS + t2] = spi[t2];
    pj[b * NPAIRS + t2] = spj[t2];
  }
  availg[b * SEQ + tid * 2] = avail[tid * 2];
  availg[b * SEQ + tid * 2 + 1] = avail[tid * 2 + 1];
}

// ---------------------------------------------------------------------------
// unmerged index list via prefix sum (ascending order)
// ---------------------------------------------------------------------------
__global__ __launch_bounds__(512)
void cc_unmerged(const unsigned char* __restrict__ availg, int* __restrict__ un) {
  int b = blockIdx.x, tid = threadIdx.x;
  __shared__ int ps[SEQ];
  int flag = availg[b * SEQ + tid];
  ps[tid] = flag;
  __syncthreads();
  for (int off = 1; off < SEQ; off <<= 1) {
    int v = (tid >= off) ? ps[tid - off] : 0;
    __syncthreads();
    ps[tid] += v;
    __syncthreads();
  }
  int pos = ps[tid] - flag;
  if (flag && pos < NUN) un[b * NUN + pos] = tid;
}

// ---------------------------------------------------------------------------
// copy unmerged tokens to out rows [128, 384)
// ---------------------------------------------------------------------------
__global__ __launch_bounds__(256)
void cc_unmerged_copy(const float* __restrict__ x, const int* __restrict__ un,
                      float* __restrict__ out) {
  int idx = blockIdx.x;
  int b = idx / NUN, u_ = idx % NUN;
  int s = un[idx];
  const float4* src = (const float4*)(x + ((size_t)b * SEQ + s) * DIM);
  float4* dst = (float4*)(out + ((size_t)b * TLEN + NPAIRS + u_) * DIM);
  for (int u = threadIdx.x; u < DIM / 4; u += 256) dst[u] = src[u];
}

// ---------------------------------------------------------------------------
// m1 = gelu(pair @ mrg_w1 + b1); pair gathered from x via pi/pj on the fly.
// 128x128 tile, 8x8 per thread, f32.
// ---------------------------------------------------------------------------
__global__ __launch_bounds__(256)
void cc_gemm_m1f(const float* __restrict__ x, const int* __restrict__ pi,
                 const int* __restrict__ pj, const float* __restrict__ B,
                 const float* __restrict__ bias, float* __restrict__ C) {
  const int N = DIM, K = 2 * DIM;
  __shared__ float As[16][132];
  __shared__ float Bs[16][132];
  int tid = threadIdx.x;
  int tx = tid % 16, ty = tid / 16;
  int m0 = blockIdx.y * 128, n0 = blockIdx.x * 128;
  float acc[8][8] = {};
  for (int k0 = 0; k0 < K; k0 += 16) {
    const int* tokArr = (k0 < DIM) ? pi : pj;
    const int kc0 = (k0 < DIM) ? k0 : k0 - DIM;
#pragma unroll
    for (int u = 0; u < 8; ++u) {
      int l = tid + u * 256;
      int r = l >> 4, k = l & 15;
      int mg = m0 + r;
      int bb = mg >> 7;
      int tok = tokArr[mg];
      As[k][r] = x[((size_t)bb * SEQ + tok) * DIM + kc0 + k];
      int kb = l >> 7, n = l & 127;
      Bs[kb][n] = B[(size_t)(k0 + kb) * N + n0 + n];
    }
    __syncthreads();
#pragma unroll
    for (int k = 0; k < 16; ++k) {
      float a[8], bb_[8];
      *(float4*)&a[0] = *(const float4*)&As[k][ty * 8];
      *(float4*)&a[4] = *(const float4*)&As[k][ty * 8 + 4];
      *(float4*)&bb_[0] = *(const float4*)&Bs[k][tx * 8];
      *(float4*)&bb_[4] = *(const float4*)&Bs[k][tx * 8 + 4];
#pragma unroll
      for (int i = 0; i < 8; ++i)
#pragma unroll
        for (int j = 0; j < 8; ++j)
          acc[i][j] = fmaf(a[i], bb_[j], acc[i][j]);
    }
    __syncthreads();
  }
#pragma unroll
  for (int i = 0; i < 8; ++i)
#pragma unroll
    for (int j = 0; j < 8; ++j) {
      int m = m0 + ty * 8 + i, n = n0 + tx * 8 + j;
      float v = acc[i][j] + bias[n];
      float g = 0.5f * v * (1.0f + erff(v * 0.70710678f));
      C[(size_t)m * N + n] = g;
    }
}

// ---------------------------------------------------------------------------
// merged = m1 @ mrg_w2 + b2, scattered into out rows [0,128). 128x128 tile.
// ---------------------------------------------------------------------------
__global__ __launch_bounds__(256)
void cc_gemm_m2c(const float* __restrict__ A, const float* __restrict__ B,
                 const float* __restrict__ bias, float* __restrict__ out) {
  const int N = DIM, K = DIM;
  __shared__ float As[16][132];
  __shared__ float Bs[16][132];
  int tid = threadIdx.x;
  int tx = tid % 16, ty = tid / 16;
  int m0 = blockIdx.y * 128, n0 = blockIdx.x * 128;
  float acc[8][8] = {};
  for (int k0 = 0; k0 < K; k0 += 16) {
#pragma unroll
    for (int u = 0; u < 8; ++u) {
      int l = tid + u * 256;
      int r = l >> 4, k = l & 15;
      As[k][r] = A[(size_t)(m0 + r) * K + k0 + k];
      int kb = l >> 7, n = l & 127;
      Bs[kb][n] = B[(size_t)(k0 + kb) * N + n0 + n];
    }
    __syncthreads();
#pragma unroll
    for (int k = 0; k < 16; ++k) {
      float a[8], bb_[8];
      *(float4*)&a[0] = *(const float4*)&As[k][ty * 8];
      *(float4*)&a[4] = *(const float4*)&As[k][ty * 8 + 4];
      *(float4*)&bb_[0] = *(const float4*)&Bs[k][tx * 8];
      *(float4*)&bb_[4] = *(const float4*)&Bs[k][tx * 8 + 4];
#pragma unroll
      for (int i = 0; i < 8; ++i)
#pragma unroll
        for (int j = 0; j < 8; ++j)
          acc[i][j] = fmaf(a[i], bb_[j], acc[i][j]);
    }
    __syncthreads();
  }
#pragma unroll
  for (int i = 0; i < 8; ++i)
#pragma unroll
    for (int j = 0; j < 8; ++j) {
      int m = m0 + ty * 8 + i, n = n0 + tx * 8 + j;
      int bb = m >> 7, p = m & 127;
      float v = acc[i][j] + bias[n];
      out[((size_t)bb * TLEN + p) * N + n] = v;
    }
}

extern "C" void kernel_launch(void* const* d_in, const int* in_sizes, int n_in,
                              void* d_out, int out_size, void* d_ws, size_t ws_size,
                              hipStream_t stream) {
  const float* x      = (const float*)d_in[0];
  const float* imp_w1 = (const float*)d_in[1];
  const float* imp_b1 = (const float*)d_in[2];
  const float* imp_w2 = (const float*)d_in[3];
  const float* imp_b2 = (const float*)d_in[4];
  const float* mrg_w1 = (const float*)d_in[5];
  const float* mrg_b1 = (const float*)d_in[6];
  const float* mrg_w2 = (const float*)d_in[7];
  const float* mrg_b2 = (const float*)d_in[8];
  float* out = (float*)d_out;

  // score (16 MB f32) lives in d_out — fully consumed before output writes.
  float* score = (float*)d_out;

  // workspace (~48.2 MB)
  char* ws = (char*)d_ws;
  float* hbuf  = (float*)ws;                               // 32 MB
  float* m1buf = (float*)(ws + ((size_t)32 << 20));        // 16 MB
  char* sm = ws + ((size_t)48 << 20);
  float* imp = (float*)sm;              sm += (size_t)BATCH * SEQ * 4;
  float* wv  = (float*)sm;              sm += (size_t)BATCH * SEQ * 4;
  float* rn  = (float*)sm;              sm += (size_t)BATCH * SEQ * 4;
  int* pi    = (int*)sm;                sm += (size_t)BATCH * NPAIRS * 4;
  int* pj    = (int*)sm;                sm += (size_t)BATCH * NPAIRS * 4;
  unsigned char* avail = (unsigned char*)sm; sm += (size_t)BATCH * SEQ;
  int* un    = (int*)sm;                sm += (size_t)BATCH * NUN * 4;

  cc_rownorm<<<BATCH * SEQ, 256, 0, stream>>>(x, rn);
  cc_gemm_h<<<dim3(HID / 64, BATCH * SEQ / 64), 256, 0, stream>>>(x, imp_w1, imp_b1, hbuf);
  cc_imp2<<<BATCH * SEQ, 256, 0, stream>>>(hbuf, imp_w2, imp_b2, imp);
  cc_minmax<<<BATCH, 512, 0, stream>>>(imp, wv);
  cc_gemm_score<<<dim3(SEQ / 64, SEQ / 64, BATCH), 256, 0, stream>>>(x, rn, wv, score);
  cc_greedy<<<BATCH, 256, 0, stream>>>(score, pi, pj, avail);
  cc_unmerged<<<BATCH, SEQ, 0, stream>>>(avail, un);
  // score (in d_out) dead from here; start writing outputs.
  cc_unmerged_copy<<<BATCH * NUN, 256, 0, stream>>>(x, un, out);
  cc_gemm_m1f<<<dim3(DIM / 128, BATCH * NPAIRS / 128), 256, 0, stream>>>(
      x, pi, pj, mrg_w1, mrg_b1, m1buf);
  cc_gemm_m2c<<<dim3(DIM / 128, BATCH * NPAIRS / 128), 256, 0, stream>>>(
      m1buf, mrg_w2, mrg_b2, out);
}